// Round 6
// baseline (245.170 us; speedup 1.0000x reference)
//
#include <hip/hip_runtime.h>

// Problem constants
#define B_ 32
#define N_ 8192
#define D_ 128
#define H_ 128
#define R_ (B_ * N_)   // 262144 rows total

#define NBLK 4096      // K1 grid: one 64-row tile per block, 128 blocks/batch

typedef _Float16 f16;
typedef __attribute__((ext_vector_type(4))) _Float16 f16x4;
typedef __attribute__((ext_vector_type(8))) _Float16 f16x8;
typedef __attribute__((ext_vector_type(4))) float f32x4;

// Workspace layout (bytes)
static constexpr size_t WPACK_OFF = 0;                            // 3*128*128 f16
static constexpr size_t VPART_OFF = 98304;                        // NBLK*128 f32 (2 MB)
static constexpr size_t SPART_OFF = VPART_OFF + (size_t)NBLK * 128 * 4;

__device__ __forceinline__ float silu_f(float v) {
    return v * __builtin_amdgcn_rcpf(1.0f + __expf(-v));
}

__device__ __forceinline__ f32x4 mfma16(f16x8 a, f16x8 b, f32x4 c) {
    return __builtin_amdgcn_mfma_f32_16x16x32_f16(a, b, c, 0, 0, 0);
}

// ---------------------------------------------------------------------------
// K0: prepack Wg1, Wn1, Wn2 (fp32 row-major [k][n] 128x128) into fp16 MFMA
// fragment order (A/B symmetric): frag[(nt*4+kc)*64 + lane][j]
//   = W[(kc*32 + (lane>>4)*8 + j)][nt*16 + (lane&15)]
// ---------------------------------------------------------------------------
__global__ void k0_prepack(const float* __restrict__ Wg1,
                           const float* __restrict__ Wn1,
                           const float* __restrict__ Wn2,
                           f16* __restrict__ wp) {
    int tid = blockIdx.x * 256 + threadIdx.x;  // 0..49151
    int m    = tid >> 14;
    int r    = tid & 16383;
    int j    = r & 7;
    int lane = (r >> 3) & 63;
    int kc   = (r >> 9) & 3;
    int nt   = r >> 11;
    int k = kc * 32 + (lane >> 4) * 8 + j;
    int n = nt * 16 + (lane & 15);
    const float* W = (m == 0) ? Wg1 : (m == 1) ? Wn1 : Wn2;
    wp[tid] = (f16)W[k * 128 + n];
}

// ---------------------------------------------------------------------------
// K1: fused, ONE barrier per block. 256 threads = 4 waves; wave w owns
// col-stripes {2w, 2w+1}. Transposed MFMA (W as A): lane holds
// D[col = st*16+q*4+r][row = mt*16+c].
// x B-fragments are loaded DIRECTLY from global per wave (4x redundant,
// L2-absorbed), register double-buffered across mt: no staging LDS, no
// barrier between load and use -> load latency overlaps MFMA within the
// wave (fine-grained vmcnt instead of the vmcnt(0)+s_barrier drain).
// Lane (q,c) B-frag for (mt,kc) = x[tb+mt*16+c][kc*32+q*8 .. +8].
// Phases: [phase1: per mt {prefetch mt+1; cvt; gate/n1 MFMA; h1->LDS,
//          gpart}] barrier [finalize exp; n2 from h1lds; V/S -> global]
// ---------------------------------------------------------------------------
__global__ __launch_bounds__(256, 2) void k1_fused(
        const float* __restrict__ x,
        const float* __restrict__ bg1, const float* __restrict__ wg2,
        const float* __restrict__ bg2, const float* __restrict__ bn1,
        const f16* __restrict__ wp,
        float* __restrict__ vpart, float* __restrict__ spart) {
    __shared__ f16 h1lds[64 * 128];
    __shared__ float gpart[4][64];

    const int tid  = threadIdx.x;
    const int w    = tid >> 6;    // wave id: stripes 2w, 2w+1
    const int lane = tid & 63;
    const int q    = lane >> 4;
    const int c    = lane & 15;

    const long rowbase = (long)blockIdx.x * 64;
    // float4 index of this lane's (mt,kc) fragment start:
    //   (rowbase + mt*16 + c)*32 + kc*8 + q*2
    const float4* __restrict__ xr = (const float4*)x;
    const long fragbase = (rowbase + c) * 32 + q * 2;

    // ---- phase-1 weight fragments (fg1, fn1; fn2 deferred) ----
    const f16x8* wpv = (const f16x8*)wp;
    f16x8 fg1[2][4], fn1[2][4];
#pragma unroll
    for (int s = 0; s < 2; ++s)
#pragma unroll
        for (int kc = 0; kc < 4; ++kc) {
            int base = ((2 * w + s) * 4 + kc) * 64 + lane;
            fg1[s][kc] = wpv[base];
            fn1[s][kc] = wpv[2048 + base];
        }
    float bg1q[2][4], wg2q[2][4], bn1q[2][4];
#pragma unroll
    for (int s = 0; s < 2; ++s)
#pragma unroll
        for (int r = 0; r < 4; ++r) {
            int col = (2 * w + s) * 16 + q * 4 + r;
            bg1q[s][r] = bg1[col];
            wg2q[s][r] = wg2[col];
            bn1q[s][r] = bn1[col];
        }
    const float bg2v = bg2[0];

    // Swizzled per-lane LDS read offsets (halves) for phase-2 frag reads
    const int loh_e = (q * 16 + (c ^ q)) * 8;        // kc even
    const int loh_o = (q * 16 + (c ^ (q | 4))) * 8;  // kc odd
    // h1 write bases for stripes st = 2w+s (kc2 = st>>1 = w)
    int h1wb[2];
#pragma unroll
    for (int s = 0; s < 2; ++s) {
        int q2 = s * 2 + (q >> 1);
        int v2 = ((w & 1) << 2) | q2;
        h1wb[s] = w * 512 + (q2 * 16 + (c ^ v2)) * 8 + (q & 1) * 4;
    }

    // ---- register double-buffer for x fragments ----
    float4 xb[2][8];  // [buf][kc*2 + half]
#pragma unroll
    for (int kc = 0; kc < 4; ++kc) {
        xb[0][kc * 2]     = xr[fragbase + kc * 8];
        xb[0][kc * 2 + 1] = xr[fragbase + kc * 8 + 1];
    }

    // ---- phase 1: gate1 + n1, loads interleaved with MFMA ----
#pragma unroll
    for (int mt = 0; mt < 4; ++mt) {
        const int cur = mt & 1, nxt = cur ^ 1;
        if (mt < 3) {
            const long fb = fragbase + (long)(mt + 1) * 16 * 32;
#pragma unroll
            for (int kc = 0; kc < 4; ++kc) {
                xb[nxt][kc * 2]     = xr[fb + kc * 8];
                xb[nxt][kc * 2 + 1] = xr[fb + kc * 8 + 1];
            }
        }
        f16x8 a[4];
#pragma unroll
        for (int kc = 0; kc < 4; ++kc) {
            float4 u = xb[cur][kc * 2], v = xb[cur][kc * 2 + 1];
            f16x8 t = {(f16)u.x, (f16)u.y, (f16)u.z, (f16)u.w,
                       (f16)v.x, (f16)v.y, (f16)v.z, (f16)v.w};
            a[kc] = t;
        }
        f32x4 ag[2] = {{0.f,0.f,0.f,0.f},{0.f,0.f,0.f,0.f}};
        f32x4 an[2] = {{0.f,0.f,0.f,0.f},{0.f,0.f,0.f,0.f}};
#pragma unroll
        for (int kc = 0; kc < 4; ++kc) {
#pragma unroll
            for (int s = 0; s < 2; ++s) {
                ag[s] = mfma16(fg1[s][kc], a[kc], ag[s]);
                an[s] = mfma16(fn1[s][kc], a[kc], an[s]);
            }
        }
        // h1: lane holds h1[row=mt*16+c][col=(2w+s)*16+q*4+r]
#pragma unroll
        for (int s = 0; s < 2; ++s) {
            f16x4 h4;
#pragma unroll
            for (int r = 0; r < 4; ++r) h4[r] = (f16)silu_f(an[s][r] + bn1q[s][r]);
            *(f16x4*)&h1lds[mt * 2048 + h1wb[s]] = h4;
        }
        // gate partial over this wave's 32 cols
        float p = 0.f;
#pragma unroll
        for (int s = 0; s < 2; ++s)
#pragma unroll
            for (int r = 0; r < 4; ++r)
                p += silu_f(ag[s][r] + bg1q[s][r]) * wg2q[s][r];
        p += __shfl_xor(p, 16);
        p += __shfl_xor(p, 32);
        if (lane < 16) gpart[w][mt * 16 + lane] = p;
    }

    // ---- issue fn2 loads: latency hides behind barrier + finalize ----
    f16x8 fn2[2][4];
#pragma unroll
    for (int s = 0; s < 2; ++s)
#pragma unroll
        for (int kc = 0; kc < 4; ++kc)
            fn2[s][kc] = wpv[4096 + ((2 * w + s) * 4 + kc) * 64 + lane];

    __syncthreads();  // the ONE barrier: gpart + h1lds ready

    // ---- finalize gate scores (redundant per wave): e for rows mt*16+c ----
    float e4[4];
#pragma unroll
    for (int mt = 0; mt < 4; ++mt) {
        float g = bg2v + gpart[0][mt * 16 + c] + gpart[1][mt * 16 + c]
                       + gpart[2][mt * 16 + c] + gpart[3][mt * 16 + c];
        e4[mt] = __expf(g);
    }

    // ---- n2 + weighted V accumulation ----
    float V[2][4] = {{0.f,0.f,0.f,0.f},{0.f,0.f,0.f,0.f}};
#pragma unroll
    for (int mt = 0; mt < 4; ++mt) {
        f16x8 b[4];
#pragma unroll
        for (int kc = 0; kc < 4; ++kc)
            b[kc] = *(const f16x8*)&h1lds[(mt * 4 + kc) * 512 +
                                          ((kc & 1) ? loh_o : loh_e)];
        f32x4 acc[2] = {{0.f,0.f,0.f,0.f},{0.f,0.f,0.f,0.f}};
#pragma unroll
        for (int kc = 0; kc < 4; ++kc)
#pragma unroll
            for (int s = 0; s < 2; ++s)
                acc[s] = mfma16(fn2[s][kc], b[kc], acc[s]);
#pragma unroll
        for (int s = 0; s < 2; ++s)
#pragma unroll
            for (int r = 0; r < 4; ++r) V[s][r] += e4[mt] * acc[s][r];
    }

    // ---- reduce over rows held by different c-lanes; write partials ----
#pragma unroll
    for (int m = 1; m < 16; m <<= 1)
#pragma unroll
        for (int s = 0; s < 2; ++s)
#pragma unroll
            for (int r = 0; r < 4; ++r) V[s][r] += __shfl_xor(V[s][r], m);
    if (c == 0) {
#pragma unroll
        for (int s = 0; s < 2; ++s) {
            float4 o = {V[s][0], V[s][1], V[s][2], V[s][3]};
            *(float4*)&vpart[(long)blockIdx.x * 128 + (2 * w + s) * 16 + q * 4] = o;
        }
    }
    if (w == 0) {
        float Sl = e4[0] + e4[1] + e4[2] + e4[3];  // rows mt*16+c (q duplicates)
#pragma unroll
        for (int m = 1; m < 16; m <<= 1) Sl += __shfl_xor(Sl, m);
        if (lane == 0) spart[blockIdx.x] = Sl;
    }
}

// ---------------------------------------------------------------------------
// K2: combine per-block partials. 32 blocks (batch) x 256 threads.
// 128 partials per batch; two half-sums per col, then merge.
// ---------------------------------------------------------------------------
__global__ void k2_combine(const float* __restrict__ vpart,
                           const float* __restrict__ spart,
                           const float* __restrict__ bn2,
                           float* __restrict__ out) {
    const int b = blockIdx.x;
    const int t = threadIdx.x;   // 0..255
    const int j = t & 127;
    const int half = t >> 7;

    const float* vp = vpart + (long)b * 128 * 128;
    float v = 0.f;
#pragma unroll
    for (int k = 0; k < 64; ++k)
        v += vp[(half * 64 + k) * 128 + j];

    __shared__ float vred[128];
    __shared__ float sred[4];
    if (half == 0) vred[j] = v;

    // denominator: threads 0..127 (2 waves) hold one spart each
    float s = (t < 128) ? spart[b * 128 + t] : 0.f;
#pragma unroll
    for (int m = 1; m < 64; m <<= 1) s += __shfl_xor(s, m);
    if (t < 128 && (t & 63) == 0) sred[t >> 6] = s;
    __syncthreads();
    if (half == 1) vred[j] += v;
    __syncthreads();
    if (t < 128) {
        float denom = sred[0] + sred[1];
        out[b * 128 + t] = vred[t] / denom + bn2[t];
    }
}

// ---------------------------------------------------------------------------
extern "C" void kernel_launch(void* const* d_in, const int* in_sizes, int n_in,
                              void* d_out, int out_size, void* d_ws, size_t ws_size,
                              hipStream_t stream) {
    const float* x   = (const float*)d_in[0];
    const float* Wg1 = (const float*)d_in[1];
    const float* bg1 = (const float*)d_in[2];
    const float* Wg2 = (const float*)d_in[3];
    const float* bg2 = (const float*)d_in[4];
    const float* Wn1 = (const float*)d_in[5];
    const float* bn1 = (const float*)d_in[6];
    const float* Wn2 = (const float*)d_in[7];
    const float* bn2 = (const float*)d_in[8];
    float* out = (float*)d_out;

    char* ws = (char*)d_ws;
    f16*   wp    = (f16*)(ws + WPACK_OFF);
    float* vpart = (float*)(ws + VPART_OFF);
    float* spart = (float*)(ws + SPART_OFF);

    k0_prepack<<<192, 256, 0, stream>>>(Wg1, Wn1, Wn2, wp);
    k1_fused<<<NBLK, 256, 0, stream>>>(x, bg1, Wg2, bg2, bn1, wp, vpart, spart);
    k2_combine<<<32, 256, 0, stream>>>(vpart, spart, bn2, out);
}

// Round 7
// 235.790 us; speedup vs baseline: 1.0398x; 1.0398x over previous
//
#include <hip/hip_runtime.h>

// Problem constants
#define B_ 32
#define N_ 8192
#define D_ 128
#define H_ 128
#define R_ (B_ * N_)   // 262144 rows total

#define NBLKA 4096     // kernel A: one 64-row tile per block
#define NBLKB 1024     // kernel B: four 64-row tiles per block

typedef _Float16 f16;
typedef __attribute__((ext_vector_type(4))) _Float16 f16x4;
typedef __attribute__((ext_vector_type(8))) _Float16 f16x8;
typedef __attribute__((ext_vector_type(4))) float f32x4;

// Workspace layout (bytes)
static constexpr size_t WPACK_OFF = 0;                      // 3*128*128 f16 = 96 KB
static constexpr size_t EWS_OFF   = 98304;                  // R_ f32 = 1 MB
static constexpr size_t VPART_OFF = EWS_OFF + (size_t)R_ * 4;        // 1024*128 f32
static constexpr size_t SPART_OFF = VPART_OFF + (size_t)NBLKB * 128 * 4; // 4096 f32
static constexpr size_t H1WS_OFF  = 2097152;                // R_*128 f16 = 64 MB

__device__ __forceinline__ float silu_f(float v) {
    return v * __builtin_amdgcn_rcpf(1.0f + __expf(-v));
}

__device__ __forceinline__ f32x4 mfma16(f16x8 a, f16x8 b, f32x4 c) {
    return __builtin_amdgcn_mfma_f32_16x16x32_f16(a, b, c, 0, 0, 0);
}

// ---------------------------------------------------------------------------
// K0: prepack Wg1, Wn1, Wn2 (fp32 row-major [k][n] 128x128) into fp16 MFMA
// fragment order (A/B symmetric): frag[(nt*4+kc)*64 + lane][j]
//   = W[(kc*32 + (lane>>4)*8 + j)][nt*16 + (lane&15)]
// ---------------------------------------------------------------------------
__global__ void k0_prepack(const float* __restrict__ Wg1,
                           const float* __restrict__ Wn1,
                           const float* __restrict__ Wn2,
                           f16* __restrict__ wp) {
    int tid = blockIdx.x * 256 + threadIdx.x;  // 0..49151
    int m    = tid >> 14;
    int r    = tid & 16383;
    int j    = r & 7;
    int lane = (r >> 3) & 63;
    int kc   = (r >> 9) & 3;
    int nt   = r >> 11;
    int k = kc * 32 + (lane >> 4) * 8 + j;
    int n = nt * 16 + (lane & 15);
    const float* W = (m == 0) ? Wg1 : (m == 1) ? Wn1 : Wn2;
    wp[tid] = (f16)W[k * 128 + n];
}

// ---------------------------------------------------------------------------
// Kernel A: gate + n1 GEMMs for one 64-row tile. 256 threads = 4 waves;
// wave w owns col-stripes {2w, 2w+1}. Transposed MFMA (W as A): lane (q,c)
// holds D[col=st*16+q*4+r][row=mt*16+c].
// h1 is stored to GLOBAL in MFMA-B-fragment order so kernel B can load it
// with coalesced dwordx4 and no layout transform:
//   h1ws[((tile*16 + mt*4 + kc)*64 + q'*16 + c)*8 + j] = h1[row=mt*16+c]
//        [k = kc*32 + q'*8 + j]
// Producer mapping: kc=w, q'=s*2+(q>>1), j=(q&1)*4+r  (verified identity).
// Each (mt,s) store: 64 lanes cover a contiguous 1 KB -> fully coalesced.
// ---------------------------------------------------------------------------
__global__ __launch_bounds__(256, 3) void k1_gate_n1(
        const float* __restrict__ x,
        const float* __restrict__ bg1, const float* __restrict__ wg2,
        const float* __restrict__ bg2, const float* __restrict__ bn1,
        const f16* __restrict__ wp,
        f16* __restrict__ h1ws, float* __restrict__ ews,
        float* __restrict__ spart) {
    __shared__ f16 xlds[64 * 128];
    __shared__ float gpart[4][64];

    const int tid  = threadIdx.x;
    const int w    = tid >> 6;    // wave id: stripes 2w, 2w+1
    const int lane = tid & 63;
    const int q    = lane >> 4;
    const int c    = lane & 15;

    // ---- issue coalesced x tile loads first (8 float4 / thread) ----
    const long rowbase = (long)blockIdx.x * 64;
    const float4* xg = (const float4*)x + rowbase * 32;
    float4 xv[8];
#pragma unroll
    for (int s = 0; s < 8; ++s) xv[s] = xg[s * 256 + tid];

    // ---- weight fragments (fg1, fn1 only) ----
    const f16x8* wpv = (const f16x8*)wp;
    f16x8 fg1[2][4], fn1[2][4];
#pragma unroll
    for (int s = 0; s < 2; ++s)
#pragma unroll
        for (int kc = 0; kc < 4; ++kc) {
            int base = ((2 * w + s) * 4 + kc) * 64 + lane;
            fg1[s][kc] = wpv[base];
            fn1[s][kc] = wpv[2048 + base];
        }
    float bg1q[2][4], wg2q[2][4], bn1q[2][4];
#pragma unroll
    for (int s = 0; s < 2; ++s)
#pragma unroll
        for (int r = 0; r < 4; ++r) {
            int col = (2 * w + s) * 16 + q * 4 + r;
            bg1q[s][r] = bg1[col];
            wg2q[s][r] = wg2[col];
            bn1q[s][r] = bn1[col];
        }
    const float bg2v = bg2[0];

    // Swizzled per-lane LDS read offsets (halves) for A-frag reads
    const int loh_e = (q * 16 + (c ^ q)) * 8;        // kc even
    const int loh_o = (q * 16 + (c ^ (q | 4))) * 8;  // kc odd
    // h1 global-store bases (halves) for stripes s=0,1
    long h1b[2];
#pragma unroll
    for (int s = 0; s < 2; ++s)
        h1b[s] = (long)blockIdx.x * 8192 +
                 (w * 64 + (s * 2 + (q >> 1)) * 16 + c) * 8 + (q & 1) * 4;

    // ---- stage x tile into swizzled frag-order LDS (xv dies here) ----
#pragma unroll
    for (int s = 0; s < 8; ++s) {
        int e   = s * 256 + tid;      // 0..2047 float4s
        int row = e >> 5, c4 = e & 31;
        int mt = row >> 4, cc = row & 15;
        int kc = c4 >> 3, qq = (c4 >> 1) & 3, j = (c4 & 1) * 4;
        int sw = (c4 >> 1) & 7;       // = (kc&1)*4 + qq
        float4 vv = xv[s];
        f16x4 hv = {(f16)vv.x, (f16)vv.y, (f16)vv.z, (f16)vv.w};
        *(f16x4*)&xlds[((mt * 4 + kc) * 64 + qq * 16 + (cc ^ sw)) * 8 + j] = hv;
    }
    __syncthreads();  // B: xlds ready

    // ---- gate1 + n1: per mt, accumulate over kc for both stripes ----
#pragma unroll
    for (int mt = 0; mt < 4; ++mt) {
        f16x8 a[4];
#pragma unroll
        for (int kc = 0; kc < 4; ++kc)
            a[kc] = *(const f16x8*)&xlds[(mt * 4 + kc) * 512 +
                                         ((kc & 1) ? loh_o : loh_e)];
        f32x4 ag[2] = {{0.f,0.f,0.f,0.f},{0.f,0.f,0.f,0.f}};
        f32x4 an[2] = {{0.f,0.f,0.f,0.f},{0.f,0.f,0.f,0.f}};
#pragma unroll
        for (int kc = 0; kc < 4; ++kc) {
#pragma unroll
            for (int s = 0; s < 2; ++s) {
                ag[s] = mfma16(fg1[s][kc], a[kc], ag[s]);
                an[s] = mfma16(fn1[s][kc], a[kc], an[s]);
            }
        }
        // h1 epilogue -> global, fragment order (coalesced dwordx2)
#pragma unroll
        for (int s = 0; s < 2; ++s) {
            f16x4 h4;
#pragma unroll
            for (int r = 0; r < 4; ++r) h4[r] = (f16)silu_f(an[s][r] + bn1q[s][r]);
            *(f16x4*)&h1ws[h1b[s] + mt * 2048] = h4;
        }
        // gate partial over this wave's 32 cols
        float p = 0.f;
#pragma unroll
        for (int s = 0; s < 2; ++s)
#pragma unroll
            for (int r = 0; r < 4; ++r)
                p += silu_f(ag[s][r] + bg1q[s][r]) * wg2q[s][r];
        p += __shfl_xor(p, 16);
        p += __shfl_xor(p, 32);
        if (lane < 16) gpart[w][mt * 16 + lane] = p;
    }
    __syncthreads();  // C: gpart ready

    // ---- wave0: finalize gate scores, write e + denom partial ----
    if (tid < 64) {
        float g = bg2v + gpart[0][tid] + gpart[1][tid]
                       + gpart[2][tid] + gpart[3][tid];
        float e = __expf(g);
        ews[rowbase + tid] = e;
        float Sl = e;
#pragma unroll
        for (int m = 1; m < 64; m <<= 1) Sl += __shfl_xor(Sl, m);
        if (tid == 0) spart[blockIdx.x] = Sl;
    }
}

// ---------------------------------------------------------------------------
// Kernel B: n2 GEMM + weighted pooling. ZERO LDS, ZERO barriers.
// 1024 blocks x 256 threads; block handles 4 tiles (256 rows). Wave w owns
// stripes {2w,2w+1}; per (tile,mt): 4 coalesced dwordx4 h1-fragment loads
// (already f16, already fragment order) + 1 e load + 8 MFMA. All 16
// iterations independent -> deep pipelining, 4 blocks/CU.
// ---------------------------------------------------------------------------
__global__ __launch_bounds__(256, 4) void k3_n2pool(
        const f16* __restrict__ h1ws, const float* __restrict__ ews,
        const f16* __restrict__ wp, float* __restrict__ vpart) {
    const int tid  = threadIdx.x;
    const int w    = tid >> 6;
    const int lane = tid & 63;
    const int q    = lane >> 4;
    const int c    = lane & 15;

    const f16x8* wpv = (const f16x8*)wp;
    f16x8 fn2[2][4];
#pragma unroll
    for (int s = 0; s < 2; ++s)
#pragma unroll
        for (int kc = 0; kc < 4; ++kc)
            fn2[s][kc] = wpv[4096 + ((2 * w + s) * 4 + kc) * 64 + lane];

    const f16x8* __restrict__ hp = (const f16x8*)h1ws;
    float V[2][4] = {{0.f,0.f,0.f,0.f},{0.f,0.f,0.f,0.f}};

    const int t0 = blockIdx.x * 4;
#pragma unroll
    for (int ti = 0; ti < 4; ++ti) {
        const long tile = t0 + ti;
#pragma unroll
        for (int mt = 0; mt < 4; ++mt) {
            const long fb = (tile * 16 + mt * 4) * 64 + lane;
            f16x8 b[4];
#pragma unroll
            for (int kc = 0; kc < 4; ++kc) b[kc] = hp[fb + kc * 64];
            float e = ews[tile * 64 + mt * 16 + c];
            f32x4 acc[2] = {{0.f,0.f,0.f,0.f},{0.f,0.f,0.f,0.f}};
#pragma unroll
            for (int kc = 0; kc < 4; ++kc)
#pragma unroll
                for (int s = 0; s < 2; ++s)
                    acc[s] = mfma16(fn2[s][kc], b[kc], acc[s]);
#pragma unroll
            for (int s = 0; s < 2; ++s)
#pragma unroll
                for (int r = 0; r < 4; ++r) V[s][r] += e * acc[s][r];
        }
    }

    // reduce across c lanes (rows); q groups hold distinct cols
#pragma unroll
    for (int m = 1; m < 16; m <<= 1)
#pragma unroll
        for (int s = 0; s < 2; ++s)
#pragma unroll
            for (int r = 0; r < 4; ++r) V[s][r] += __shfl_xor(V[s][r], m);
    if (c == 0) {
#pragma unroll
        for (int s = 0; s < 2; ++s) {
            float4 o = {V[s][0], V[s][1], V[s][2], V[s][3]};
            *(float4*)&vpart[(long)blockIdx.x * 128 + (2 * w + s) * 16 + q * 4] = o;
        }
    }
}

// ---------------------------------------------------------------------------
// K2: combine. 32 blocks (batch) x 128 threads (col).
// Per batch: 32 vpart rows (kernel B) and 128 spart entries (kernel A).
// bn2 folded in (sum attn == 1).
// ---------------------------------------------------------------------------
__global__ void k2_combine(const float* __restrict__ vpart,
                           const float* __restrict__ spart,
                           const float* __restrict__ bn2,
                           float* __restrict__ out) {
    const int b = blockIdx.x;
    const int t = threadIdx.x;   // 0..127

    float v = 0.f;
#pragma unroll
    for (int k = 0; k < 32; ++k)
        v += vpart[(long)(b * 32 + k) * 128 + t];

    float s = spart[b * 128 + t];
#pragma unroll
    for (int m = 1; m < 64; m <<= 1) s += __shfl_xor(s, m);
    __shared__ float sred[2];
    if ((t & 63) == 0) sred[t >> 6] = s;
    __syncthreads();
    float denom = sred[0] + sred[1];
    out[b * 128 + t] = v / denom + bn2[t];
}

// ---------------------------------------------------------------------------
extern "C" void kernel_launch(void* const* d_in, const int* in_sizes, int n_in,
                              void* d_out, int out_size, void* d_ws, size_t ws_size,
                              hipStream_t stream) {
    const float* x   = (const float*)d_in[0];
    const float* Wg1 = (const float*)d_in[1];
    const float* bg1 = (const float*)d_in[2];
    const float* Wg2 = (const float*)d_in[3];
    const float* bg2 = (const float*)d_in[4];
    const float* Wn1 = (const float*)d_in[5];
    const float* bn1 = (const float*)d_in[6];
    const float* Wn2 = (const float*)d_in[7];
    const float* bn2 = (const float*)d_in[8];
    float* out = (float*)d_out;

    char* ws = (char*)d_ws;
    f16*   wp    = (f16*)(ws + WPACK_OFF);
    float* ews   = (float*)(ws + EWS_OFF);
    float* vpart = (float*)(ws + VPART_OFF);
    float* spart = (float*)(ws + SPART_OFF);
    f16*   h1ws  = (f16*)(ws + H1WS_OFF);

    k0_prepack<<<192, 256, 0, stream>>>(Wg1, Wn1, Wn2, wp);
    k1_gate_n1<<<NBLKA, 256, 0, stream>>>(x, bg1, Wg2, bg2, bn1, wp,
                                          h1ws, ews, spart);
    k3_n2pool<<<NBLKB, 256, 0, stream>>>(h1ws, ews, wp, vpart);
    k2_combine<<<32, 128, 0, stream>>>(vpart, spart, bn2, out);
}